// Round 14
// baseline (103.584 us; speedup 1.0000x reference)
//
#include <hip/hip_runtime.h>

// FFF tree traversal, round 14: TWO ROWS PER WAVE (ILP2, spill-free this
// time). r13 proved VALU isn't binding (removed 14 ops/level -> flat time,
// VALUBusy 67->53%): the kernel is latency-exposure-bound on the per-level
// serial chain (dot -> reduce -> sign -> ~250cy L2 gather). Two independent
// row-chains per wave interleave to cover each other's stalls.
// Enabler: i8 x (4 dwords/row vs 16 for fp32) + NO registered fp32 xv —
// the rare wave-uniform EPS fallback reloads x from global (same bits).
// Peak live state ~90 VGPR -> no spill (r2/r5/r6's 2-row failure mode).
// Frozen: rolled loop, DPP reduces, next-level load before y-accum, single-
// node loads (no both-children prefetch), nt x loads, plain y stores,
// signed-i8 w1 + sdot4, biased-u8 w2 + corr, EPS=0.035 fp32 fallback.

typedef float        f32x4 __attribute__((ext_vector_type(4)));
typedef unsigned int u32x4 __attribute__((ext_vector_type(4)));

#define FFF_BATCH  32768
#define FFF_NIN    1024
#define FFF_NOUT   1024
#define FFF_LEVELS 11
#define FFF_NODES  2047
#define FFF_EPS    0.035f

__device__ __forceinline__ f32x4 ld_nt4f(const f32x4* p) { return __builtin_nontemporal_load(p); }
__device__ __forceinline__ float ub(unsigned d, int k) {
    return (float)((d >> (8 * k)) & 0xffu);   // -> v_cvt_f32_ubyte[k]
}

__device__ __forceinline__ int sdot4(unsigned a, unsigned b, int c) {
#if __has_builtin(__builtin_amdgcn_sdot4)
    return __builtin_amdgcn_sdot4((int)a, (int)b, c, false);
#else
#pragma unroll
    for (int k = 0; k < 4; ++k) {
        const int ai = (int)(a << (24 - 8 * k)) >> 24;
        const int bi = (int)(b << (24 - 8 * k)) >> 24;
        c += ai * bi;
    }
    return c;
#endif
}

template<int CTRL>
__device__ __forceinline__ float dpp_add(float v) {
    const int t = __builtin_amdgcn_update_dpp(0, __float_as_int(v), CTRL, 0xF, 0xF, true);
    return v + __int_as_float(t);
}
__device__ __forceinline__ float wave_sum(float v) {
    v = dpp_add<0x111>(v); v = dpp_add<0x112>(v);
    v = dpp_add<0x114>(v); v = dpp_add<0x118>(v);
    v = dpp_add<0x142>(v); v = dpp_add<0x143>(v);
    return __int_as_float(__builtin_amdgcn_readlane(__float_as_int(v), 63));
}
template<int CTRL>
__device__ __forceinline__ int dpp_addi(int v) {
    return v + __builtin_amdgcn_update_dpp(0, v, CTRL, 0xF, 0xF, true);
}
// interleaved dual integer reduce (two independent DPP chains)
__device__ __forceinline__ void wave_sum_i2(int& a, int& b) {
    a = dpp_addi<0x111>(a); b = dpp_addi<0x111>(b);
    a = dpp_addi<0x112>(a); b = dpp_addi<0x112>(b);
    a = dpp_addi<0x114>(a); b = dpp_addi<0x114>(b);
    a = dpp_addi<0x118>(a); b = dpp_addi<0x118>(b);
    a = dpp_addi<0x142>(a); b = dpp_addi<0x142>(b);
    a = dpp_addi<0x143>(a); b = dpp_addi<0x143>(b);
    a = __builtin_amdgcn_readlane(a, 63);
    b = __builtin_amdgcn_readlane(b, 63);
}
template<int CTRL>
__device__ __forceinline__ float dpp_max(float v) {
    const int t = __builtin_amdgcn_update_dpp(0, __float_as_int(v), CTRL, 0xF, 0xF, true);
    return fmaxf(v, __int_as_float(t));
}
__device__ __forceinline__ float wave_max(float v) {   // v >= 0
    v = dpp_max<0x111>(v); v = dpp_max<0x112>(v);
    v = dpp_max<0x114>(v); v = dpp_max<0x118>(v);
    v = dpp_max<0x142>(v); v = dpp_max<0x143>(v);
    return __int_as_float(__builtin_amdgcn_readlane(__float_as_int(v), 63));
}

// ---- prep: w1 -> signed i8, w2 -> biased u8 (one block per node) ----
// byte b = 4*t + k of node's 1024B row <- src elem 256*(t&3) + 4*(t>>2) + k,
// so in main, lane's dwords 4*lane..+3 pair with xq[c][k] <- x[256c+4*lane+k].
__global__ void fff_quant_u8(const float* __restrict__ w1, const float* __restrict__ w2,
                             unsigned char* __restrict__ q1, unsigned char* __restrict__ q2,
                             float* __restrict__ s1, float* __restrict__ s2)
{
    const int node = blockIdx.x;
    const int t    = threadIdx.x;          // 256
    const int wave = t >> 6;
    const int lane = t & 63;

    const f32x4* r1 = reinterpret_cast<const f32x4*>(w1 + (size_t)node * FFF_NIN);
    const f32x4* r2 = reinterpret_cast<const f32x4*>(w2 + (size_t)node * FFF_NOUT);
    const int si = 64 * (t & 3) + (t >> 2);
    const f32x4 v1 = r1[si];
    const f32x4 v2 = r2[si];

    float m1 = 0.f, m2 = 0.f;
#pragma unroll
    for (int k = 0; k < 4; ++k) {
        m1 = fmaxf(m1, fabsf(v1[k]));
        m2 = fmaxf(m2, fabsf(v2[k]));
    }
#pragma unroll
    for (int m = 1; m < 64; m <<= 1) {
        m1 = fmaxf(m1, __shfl_xor(m1, m, 64));
        m2 = fmaxf(m2, __shfl_xor(m2, m, 64));
    }
    __shared__ float sm1[4], sm2[4];
    if (lane == 0) { sm1[wave] = m1; sm2[wave] = m2; }
    __syncthreads();
    m1 = fmaxf(fmaxf(sm1[0], sm1[1]), fmaxf(sm1[2], sm1[3]));
    m2 = fmaxf(fmaxf(sm2[0], sm2[1]), fmaxf(sm2[2], sm2[3]));

    const float st1 = (m1 > 0.f) ? m1 / 127.f : 1.f;
    const float st2 = (m2 > 0.f) ? m2 / 127.f : 1.f;
    if (t == 0) { s1[node] = st1; s2[node] = st2; }

    unsigned d1 = 0, d2 = 0;
#pragma unroll
    for (int k = 0; k < 4; ++k) {
        const int i1 = (int)rintf(v1[k] / st1);         // signed, [-127,127]
        const int u2 = (int)rintf(v2[k] / st2) + 128;   // biased, [1,255]
        d1 |= ((unsigned)i1 & 0xffu) << (8 * k);
        d2 |= ((unsigned)u2 & 0xffu) << (8 * k);
    }
    reinterpret_cast<unsigned*>(q1)[(size_t)node * 256 + t] = d1;
    reinterpret_cast<unsigned*>(q2)[(size_t)node * 256 + t] = d2;
}

// ---- main fused kernel: 2 rows per wave, rolled level loop ----
__global__ __launch_bounds__(256, 4) void fff_main_u8(
    const float*         __restrict__ x,
    const unsigned char* __restrict__ q1,
    const float*         __restrict__ s1,
    const float*         __restrict__ w1f,   // fp32 w1 for the EPS fallback
    const unsigned char* __restrict__ q2,
    const float*         __restrict__ s2,
    float*               __restrict__ y)
{
    const int wave = threadIdx.x >> 6;
    const int lane = threadIdx.x & 63;
    const int row0 = (blockIdx.x * 4 + wave) * 2;

    const f32x4* x4a = reinterpret_cast<const f32x4*>(x + (size_t)row0 * FFF_NIN);
    const f32x4* x4b = reinterpret_cast<const f32x4*>(x + (size_t)(row0 + 1) * FFF_NIN);

    // quantize both rows to i8; fp32 x is NOT kept live (fallback reloads)
    unsigned xqa[4], xqb[4];
    float stxa, stxb;
    {
        f32x4 xa[4], xb[4];
#pragma unroll
        for (int c = 0; c < 4; ++c) {
            xa[c] = ld_nt4f(&x4a[c * 64 + lane]);
            xb[c] = ld_nt4f(&x4b[c * 64 + lane]);
        }
        float ma = 0.f, mb = 0.f;
#pragma unroll
        for (int c = 0; c < 4; ++c)
#pragma unroll
            for (int k = 0; k < 4; ++k) {
                ma = fmaxf(ma, fabsf(xa[c][k]));
                mb = fmaxf(mb, fabsf(xb[c][k]));
            }
        ma = wave_max(ma); mb = wave_max(mb);
        stxa = (ma > 0.f) ? ma / 127.f : 1.f;
        stxb = (mb > 0.f) ? mb / 127.f : 1.f;
        const float ia = (ma > 0.f) ? 127.f / ma : 0.f;
        const float ib = (mb > 0.f) ? 127.f / mb : 0.f;
#pragma unroll
        for (int c = 0; c < 4; ++c) {
            unsigned pa = 0, pb = 0;
#pragma unroll
            for (int k = 0; k < 4; ++k) {
                pa |= ((unsigned)(int)rintf(xa[c][k] * ia) & 0xffu) << (8 * k);
                pb |= ((unsigned)(int)rintf(xb[c][k] * ib) & 0xffu) << (8 * k);
            }
            xqa[c] = pa; xqb[c] = pb;
        }
    }

    f32x4 accA[4], accB[4];
#pragma unroll
    for (int c = 0; c < 4; ++c) { accA[c] = (f32x4)(0.f); accB[c] = (f32x4)(0.f); }
    float corrA = 0.f, corrB = 0.f;

    const u32x4* q1v = reinterpret_cast<const u32x4*>(q1);  // node*64 + lane
    const u32x4* q2v = reinterpret_cast<const u32x4*>(q2);

    int nodeA = 0, nodeB = 0;
    u32x4 d1a = q1v[lane];
    u32x4 d2a = q2v[lane];
    u32x4 d1b = d1a, d2b = d2a;            // both rows start at node 0
    float s1a = s1[0], s2a = s2[0];
    float s1b = s1a, s2b = s2a;

#pragma unroll 1
    for (int l = 0; l < FFF_LEVELS; ++l) {
        // ---- dual i8 dots (independent chains) ----
        int ia = 0, ib = 0;
#pragma unroll
        for (int c = 0; c < 4; ++c) {
            ia = sdot4(xqa[c], d1a[c], ia);
            ib = sdot4(xqb[c], d1b[c], ib);
        }
        wave_sum_i2(ia, ib);
        float pA = (float)ia * (stxa * s1a);
        float pB = (float)ib * (stxb * s1b);

        // ---- rare wave-uniform fp32 recompute (x reloaded from global) ----
        if (__builtin_expect(fabsf(pA) < FFF_EPS, 0)) {
            const f32x4* w14 = reinterpret_cast<const f32x4*>(w1f + (size_t)nodeA * FFF_NIN);
            float s = 0.f;
#pragma unroll
            for (int c = 0; c < 4; ++c) {
                const f32x4 xc = ld_nt4f(&x4a[c * 64 + lane]);
                const f32x4 w  = w14[c * 64 + lane];
                s = fmaf(xc[0], w[0], s);
                s = fmaf(xc[1], w[1], s);
                s = fmaf(xc[2], w[2], s);
                s = fmaf(xc[3], w[3], s);
            }
            pA = wave_sum(s);
        }
        if (__builtin_expect(fabsf(pB) < FFF_EPS, 0)) {
            const f32x4* w14 = reinterpret_cast<const f32x4*>(w1f + (size_t)nodeB * FFF_NIN);
            float s = 0.f;
#pragma unroll
            for (int c = 0; c < 4; ++c) {
                const f32x4 xc = ld_nt4f(&x4b[c * 64 + lane]);
                const f32x4 w  = w14[c * 64 + lane];
                s = fmaf(xc[0], w[0], s);
                s = fmaf(xc[1], w[1], s);
                s = fmaf(xc[2], w[2], s);
                s = fmaf(xc[3], w[3], s);
            }
            pB = wave_sum(s);
        }

        // ---- advance + issue BOTH rows' next-level loads before y-accum ----
        const int nextA = 2 * nodeA + 1 + ((pA > 0.f) ? 1 : 0);
        const int nextB = 2 * nodeB + 1 + ((pB > 0.f) ? 1 : 0);
        u32x4 nd1a = d1a, nd2a = d2a, nd1b = d1b, nd2b = d2b;
        float ns1a = s1a, ns2a = s2a, ns1b = s1b, ns2b = s2b;
        if (l < FFF_LEVELS - 1) {
            const int ua = __builtin_amdgcn_readfirstlane(nextA);
            const int ub_ = __builtin_amdgcn_readfirstlane(nextB);
            nd1a = q1v[(size_t)ua * 64 + lane];
            nd2a = q2v[(size_t)ua * 64 + lane];
            nd1b = q1v[(size_t)ub_ * 64 + lane];
            nd2b = q2v[(size_t)ub_ * 64 + lane];
            ns1a = s1[ua]; ns2a = s2[ua];
            ns1b = s1[ub_]; ns2b = s2[ub_];
        }

        // ---- dual y-accum (hides the child-load latency) ----
        const float fA = pA * s2a;
        const float fB = pB * s2b;
        corrA = fmaf(fA, 128.f, corrA);
        corrB = fmaf(fB, 128.f, corrB);
#pragma unroll
        for (int c = 0; c < 4; ++c) {
#pragma unroll
            for (int k = 0; k < 4; ++k) {
                accA[c][k] = fmaf(fA, ub(d2a[c], k), accA[c][k]);
                accB[c][k] = fmaf(fB, ub(d2b[c], k), accB[c][k]);
            }
        }

        nodeA = nextA; nodeB = nextB;
        d1a = nd1a; d2a = nd2a; d1b = nd1b; d2b = nd2b;
        s1a = ns1a; s2a = ns2a; s1b = ns1b; s2b = ns2b;
    }

    // coalesced y stores, subtracting the uniform bias corrections
    f32x4* y4a = reinterpret_cast<f32x4*>(y + (size_t)row0 * FFF_NOUT);
    f32x4* y4b = reinterpret_cast<f32x4*>(y + (size_t)(row0 + 1) * FFF_NOUT);
#pragma unroll
    for (int c = 0; c < 4; ++c) {
        f32x4 oa, ob;
#pragma unroll
        for (int k = 0; k < 4; ++k) { oa[k] = accA[c][k] - corrA; ob[k] = accB[c][k] - corrB; }
        y4a[c * 64 + lane] = oa;
        y4b[c * 64 + lane] = ob;
    }
}

// ---- safety fallback: proven round-1 fp32 fused kernel ----
__global__ __launch_bounds__(256, 4) void fff_fused_f32(
    const float* __restrict__ x, const float* __restrict__ w1s,
    const float* __restrict__ w2s, float* __restrict__ y)
{
    const int row  = blockIdx.x * 4 + (threadIdx.x >> 6);
    const int lane = threadIdx.x & 63;
    const f32x4* x4 = reinterpret_cast<const f32x4*>(x + (size_t)row * FFF_NIN);
    f32x4 xv[4];
#pragma unroll
    for (int c = 0; c < 4; ++c) xv[c] = x4[c * 64 + lane];
    f32x4 acc[4];
#pragma unroll
    for (int c = 0; c < 4; ++c) acc[c] = (f32x4)(0.f);
    int node = 0;
#pragma unroll 1
    for (int l = 0; l < FFF_LEVELS; ++l) {
        const f32x4* w14 = reinterpret_cast<const f32x4*>(w1s + (size_t)node * FFF_NIN);
        const f32x4* w24 = reinterpret_cast<const f32x4*>(w2s + (size_t)node * FFF_NOUT);
        f32x4 wv[4], uv[4];
#pragma unroll
        for (int c = 0; c < 4; ++c) { wv[c] = w14[c * 64 + lane]; uv[c] = w24[c * 64 + lane]; }
        float p = 0.f;
#pragma unroll
        for (int c = 0; c < 4; ++c) {
            p = fmaf(xv[c][0], wv[c][0], p); p = fmaf(xv[c][1], wv[c][1], p);
            p = fmaf(xv[c][2], wv[c][2], p); p = fmaf(xv[c][3], wv[c][3], p);
        }
#pragma unroll
        for (int m = 1; m < 64; m <<= 1) p += __shfl_xor(p, m, 64);
#pragma unroll
        for (int c = 0; c < 4; ++c) {
            acc[c][0] = fmaf(p, uv[c][0], acc[c][0]); acc[c][1] = fmaf(p, uv[c][1], acc[c][1]);
            acc[c][2] = fmaf(p, uv[c][2], acc[c][2]); acc[c][3] = fmaf(p, uv[c][3], acc[c][3]);
        }
        node = node * 2 + 1 + ((p > 0.f) ? 1 : 0);
    }
    f32x4* y4 = reinterpret_cast<f32x4*>(y + (size_t)row * FFF_NOUT);
#pragma unroll
    for (int c = 0; c < 4; ++c) y4[c * 64 + lane] = acc[c];
}

extern "C" void kernel_launch(void* const* d_in, const int* in_sizes, int n_in,
                              void* d_out, int out_size, void* d_ws, size_t ws_size,
                              hipStream_t stream) {
    const float* x   = (const float*)d_in[0];
    const float* w1s = (const float*)d_in[1];
    const float* w2s = (const float*)d_in[2];
    float* y = (float*)d_out;

    // ws layout (16B-aligned blocks): s1 | s2 | q1 | q2
    const size_t sc_bytes = 8192;                              // 2047 floats, padded
    const size_t q_bytes  = (size_t)FFF_NODES * 1024;          // 2,096,128
    const size_t need = 2 * sc_bytes + 2 * q_bytes;            // ~4.21 MB

    if (ws_size >= need) {
        float* s1 = (float*)d_ws;
        float* s2 = (float*)((char*)d_ws + sc_bytes);
        unsigned char* q1 = (unsigned char*)d_ws + 2 * sc_bytes;
        unsigned char* q2 = q1 + q_bytes;
        fff_quant_u8<<<FFF_NODES, 256, 0, stream>>>(w1s, w2s, q1, q2, s1, s2);
        // 4 waves/block x 2 rows/wave = 8 rows/block -> 4096 blocks
        fff_main_u8<<<FFF_BATCH / 8, 256, 0, stream>>>(x, q1, s1, w1s, q2, s2, y);
    } else {
        fff_fused_f32<<<FFF_BATCH / 4, 256, 0, stream>>>(x, w1s, w2s, y);
    }
}